// Round 1
// baseline (476.069 us; speedup 1.0000x reference)
//
#include <hip/hip_runtime.h>

#define RDIM 1152
#define CIN  8
#define COUT 16
#define CDIM 10
#define BDIM 256
#define BLOCK 384
#define ROWS 3          // RDIM / BLOCK
#define NWAVES (BLOCK / 64)
#define EPS 1e-7f

__global__ __launch_bounds__(BLOCK) void caps_route(
    const float* __restrict__ x, const float* __restrict__ W,
    float* __restrict__ out)
{
    const int wg  = blockIdx.x;      // 0 .. C*B-1
    const int c   = wg / BDIM;
    const int b   = wg % BDIM;
    const int tid = threadIdx.x;
    const int lane = tid & 63;
    const int wave = tid >> 6;

    __shared__ float red[NWAVES][COUT];
    __shared__ float scalm[NWAVES];
    __shared__ float scalz[NWAVES];

    const float* __restrict__ Wc = W + (size_t)c * RDIM * CIN * COUT;
    const float* __restrict__ xb = x + (size_t)b * RDIM * CIN;

    float uh[ROWS][COUT];
    float bb[ROWS];

    // ---- compute u_hat rows owned by this thread (r = tid + k*BLOCK) ----
    #pragma unroll
    for (int k = 0; k < ROWS; ++k) {
        const int r = tid + k * BLOCK;
        const float4* xp = (const float4*)(xb + (size_t)r * CIN);
        float4 x0 = xp[0], x1 = xp[1];
        float xr[CIN] = {x0.x, x0.y, x0.z, x0.w, x1.x, x1.y, x1.z, x1.w};

        #pragma unroll
        for (int o = 0; o < COUT; ++o) uh[k][o] = 0.0f;

        const float4* wp = (const float4*)(Wc + (size_t)r * CIN * COUT);
        #pragma unroll
        for (int i = 0; i < CIN; ++i) {
            float xi = xr[i];
            #pragma unroll
            for (int oq = 0; oq < 4; ++oq) {
                float4 w = wp[i * 4 + oq];
                uh[k][oq * 4 + 0] = fmaf(xi, w.x, uh[k][oq * 4 + 0]);
                uh[k][oq * 4 + 1] = fmaf(xi, w.y, uh[k][oq * 4 + 1]);
                uh[k][oq * 4 + 2] = fmaf(xi, w.z, uh[k][oq * 4 + 2]);
                uh[k][oq * 4 + 3] = fmaf(xi, w.w, uh[k][oq * 4 + 3]);
            }
        }
        bb[k] = 0.0f;
    }

    float v[COUT];

    // ---- 3 routing iterations ----
    #pragma unroll
    for (int it = 0; it < 3; ++it) {
        // 1) max of b over R (for stable softmax, matching jax.nn.softmax)
        float m = bb[0];
        #pragma unroll
        for (int k = 1; k < ROWS; ++k) m = fmaxf(m, bb[k]);
        #pragma unroll
        for (int off = 32; off >= 1; off >>= 1) m = fmaxf(m, __shfl_xor(m, off));
        if (lane == 0) scalm[wave] = m;
        __syncthreads();
        m = scalm[0];
        #pragma unroll
        for (int w = 1; w < NWAVES; ++w) m = fmaxf(m, scalm[w]);

        // 2) e = exp(b-m); partial Z and partial weighted sum s
        float e[ROWS];
        float Zp = 0.0f;
        float sp[COUT];
        #pragma unroll
        for (int o = 0; o < COUT; ++o) sp[o] = 0.0f;
        #pragma unroll
        for (int k = 0; k < ROWS; ++k) {
            e[k] = expf(bb[k] - m);
            Zp += e[k];
            #pragma unroll
            for (int o = 0; o < COUT; ++o)
                sp[o] = fmaf(e[k], uh[k][o], sp[o]);
        }
        // wave butterfly reduce
        #pragma unroll
        for (int off = 32; off >= 1; off >>= 1) {
            Zp += __shfl_xor(Zp, off);
            #pragma unroll
            for (int o = 0; o < COUT; ++o) sp[o] += __shfl_xor(sp[o], off);
        }
        if (lane == 0) {
            scalz[wave] = Zp;
            #pragma unroll
            for (int o = 0; o < COUT; ++o) red[wave][o] = sp[o];
        }
        __syncthreads();

        // 3) final reduce (redundant on every thread; LDS broadcast reads)
        float Z = 0.0f;
        #pragma unroll
        for (int w = 0; w < NWAVES; ++w) Z += scalz[w];
        float invZ = 1.0f / Z;
        float s[COUT];
        float sn = 0.0f;
        #pragma unroll
        for (int o = 0; o < COUT; ++o) {
            float acc = 0.0f;
            #pragma unroll
            for (int w = 0; w < NWAVES; ++w) acc += red[w][o];
            acc *= invZ;
            s[o] = acc;
            sn = fmaf(acc, acc, sn);
        }
        // squash: v = (sn/(1+sn)) * s / sqrt(sn+eps)
        float scale = (sn / (1.0f + sn)) / sqrtf(sn + EPS);
        #pragma unroll
        for (int o = 0; o < COUT; ++o) v[o] = scale * s[o];

        // 4) agreement update (not on last iteration)
        if (it < 2) {
            #pragma unroll
            for (int k = 0; k < ROWS; ++k) {
                float a = 0.0f;
                #pragma unroll
                for (int o = 0; o < COUT; ++o) a = fmaf(uh[k][o], v[o], a);
                bb[k] += a;
            }
        }
    }

    // ---- write output [C,B,1,1,O] ----
    if (tid < COUT)
        out[((size_t)c * BDIM + b) * COUT + tid] = v[tid];
}

extern "C" void kernel_launch(void* const* d_in, const int* in_sizes, int n_in,
                              void* d_out, int out_size, void* d_ws, size_t ws_size,
                              hipStream_t stream) {
    const float* x = (const float*)d_in[0];   // [256,1152,8]
    const float* W = (const float*)d_in[1];   // [10,1152,8,16]
    float* out = (float*)d_out;               // [10,256,1,1,16]

    dim3 grid(CDIM * BDIM);
    dim3 block(BLOCK);
    caps_route<<<grid, block, 0, stream>>>(x, W, out);
}

// Round 2
// 455.785 us; speedup vs baseline: 1.0445x; 1.0445x over previous
//
#include <hip/hip_runtime.h>

#define RDIM 1152
#define CIN  8
#define COUT 16
#define CDIM 10
#define BDIM 256
#define BLOCK 384
#define UNITS 12                 // (1152 rows * 4 o-quarters) / 384 threads
#define NWAVES (BLOCK / 64)
#define NWG (CDIM * BDIM)        // 2560, divisible by 8
#define EPS 1e-7f

__global__ __launch_bounds__(BLOCK) void caps_route(
    const float* __restrict__ x, const float* __restrict__ W,
    float* __restrict__ out)
{
    // XCD-aware bijective swizzle: 2560 = 8 * 320 -> each XCD gets a
    // contiguous wgid range (~1.25 c's worth -> W[c] L2-resident per XCD)
    const int orig = blockIdx.x;
    const int wg   = (orig & 7) * (NWG / 8) + (orig >> 3);
    const int c    = wg / BDIM;
    const int b    = wg % BDIM;

    const int tid  = threadIdx.x;
    const int lane = tid & 63;
    const int wave = tid >> 6;
    const int oq   = tid & 3;     // owned o-quarter (o = oq*4 .. oq*4+3)
    const int rsub = tid >> 2;    // 0..95 row-within-group

    __shared__ float red[NWAVES][COUT];
    __shared__ float scalm[NWAVES];
    __shared__ float scalz[NWAVES];

    const float* __restrict__ Wc = W + (size_t)c * RDIM * CIN * COUT;
    const float* __restrict__ xb = x + (size_t)b * RDIM * CIN;

    float uh[UNITS][4];   // u_hat[r_k][oq*4 .. +3]
    float bb[UNITS];      // routing logits (duplicated x4 across oq lanes)

    // ---- u_hat: coalesced W reads (4 lanes cover 64B, groups stride 512B) ----
    #pragma unroll
    for (int k = 0; k < UNITS; ++k) {
        const int r = k * 96 + rsub;
        const float4* xp = (const float4*)(xb + (size_t)r * CIN);
        float4 x0 = xp[0], x1 = xp[1];
        float xr[CIN] = {x0.x, x0.y, x0.z, x0.w, x1.x, x1.y, x1.z, x1.w};

        const float* wrow = Wc + (size_t)r * (CIN * COUT) + oq * 4;
        float a0 = 0.f, a1 = 0.f, a2 = 0.f, a3 = 0.f;
        #pragma unroll
        for (int i = 0; i < CIN; ++i) {
            float4 w = *(const float4*)(wrow + i * COUT);
            a0 = fmaf(xr[i], w.x, a0);
            a1 = fmaf(xr[i], w.y, a1);
            a2 = fmaf(xr[i], w.z, a2);
            a3 = fmaf(xr[i], w.w, a3);
        }
        uh[k][0] = a0; uh[k][1] = a1; uh[k][2] = a2; uh[k][3] = a3;
        bb[k] = 0.0f;
    }

    float vq[4];   // thread's 4-float slice of squashed output

    #pragma unroll
    for (int it = 0; it < 3; ++it) {
        // ---- 1) softmax max over R ----
        float m = bb[0];
        #pragma unroll
        for (int k = 1; k < UNITS; ++k) m = fmaxf(m, bb[k]);
        #pragma unroll
        for (int off = 32; off >= 1; off >>= 1) m = fmaxf(m, __shfl_xor(m, off));
        if (lane == 0) scalm[wave] = m;
        __syncthreads();
        m = scalm[0];
        #pragma unroll
        for (int w2 = 1; w2 < NWAVES; ++w2) m = fmaxf(m, scalm[w2]);

        // ---- 2) e = exp(b-m); partial Z and weighted o-slice sums ----
        float e[UNITS];
        float Zp = 0.f, sp0 = 0.f, sp1 = 0.f, sp2 = 0.f, sp3 = 0.f;
        #pragma unroll
        for (int k = 0; k < UNITS; ++k) {
            e[k] = expf(bb[k] - m);
            Zp += e[k];
            sp0 = fmaf(e[k], uh[k][0], sp0);
            sp1 = fmaf(e[k], uh[k][1], sp1);
            sp2 = fmaf(e[k], uh[k][2], sp2);
            sp3 = fmaf(e[k], uh[k][3], sp3);
        }
        // butterfly over same-oq lanes (xor 4..32 keeps lane%4 invariant);
        // each same-oq set covers 192 distinct rows exactly once
        #pragma unroll
        for (int off = 32; off >= 4; off >>= 1) {
            Zp  += __shfl_xor(Zp, off);
            sp0 += __shfl_xor(sp0, off);
            sp1 += __shfl_xor(sp1, off);
            sp2 += __shfl_xor(sp2, off);
            sp3 += __shfl_xor(sp3, off);
        }
        if (lane < 4) {   // lane == oq here; its slice is o = lane*4..+3
            red[wave][lane * 4 + 0] = sp0;
            red[wave][lane * 4 + 1] = sp1;
            red[wave][lane * 4 + 2] = sp2;
            red[wave][lane * 4 + 3] = sp3;
            if (lane == 0) scalz[wave] = Zp;
        }
        __syncthreads();

        // ---- 3) finalize s, squash ----
        float Z = 0.f;
        #pragma unroll
        for (int w2 = 0; w2 < NWAVES; ++w2) Z += scalz[w2];
        const float invZ = 1.0f / Z;

        float sn = 0.f;
        #pragma unroll
        for (int o = 0; o < COUT; ++o) {
            float acc = 0.f;
            #pragma unroll
            for (int w2 = 0; w2 < NWAVES; ++w2) acc += red[w2][o];
            acc *= invZ;
            sn = fmaf(acc, acc, sn);
        }
        const float scale = (sn / (1.0f + sn)) / sqrtf(sn + EPS);

        // thread's own v slice (LDS runtime index is fine; registers stay static)
        #pragma unroll
        for (int j = 0; j < 4; ++j) {
            float acc = 0.f;
            #pragma unroll
            for (int w2 = 0; w2 < NWAVES; ++w2) acc += red[w2][oq * 4 + j];
            vq[j] = acc * invZ * scale;
        }

        // ---- 4) agreement update ----
        if (it < 2) {
            #pragma unroll
            for (int k = 0; k < UNITS; ++k) {
                float a = uh[k][0] * vq[0];
                a = fmaf(uh[k][1], vq[1], a);
                a = fmaf(uh[k][2], vq[2], a);
                a = fmaf(uh[k][3], vq[3], a);
                // complete the 16-o dot across the 4 lanes sharing row r
                a += __shfl_xor(a, 1);
                a += __shfl_xor(a, 2);
                bb[k] += a;
            }
            __syncthreads();  // protect red/scalz before next iteration's writes
        }
    }

    // ---- write output [C,B,1,1,O]: thread tid<16 writes o = oq*4 + rsub ----
    if (tid < 16) {
        const size_t base = ((size_t)c * BDIM + b) * COUT;
        #pragma unroll
        for (int j = 0; j < 4; ++j)
            if (rsub == j) out[base + oq * 4 + j] = vq[j];
    }
}

extern "C" void kernel_launch(void* const* d_in, const int* in_sizes, int n_in,
                              void* d_out, int out_size, void* d_ws, size_t ws_size,
                              hipStream_t stream) {
    const float* x = (const float*)d_in[0];   // [256,1152,8]
    const float* W = (const float*)d_in[1];   // [10,1152,8,16]
    float* out = (float*)d_out;               // [10,256,1,1,16]

    dim3 grid(NWG);
    dim3 block(BLOCK);
    caps_route<<<grid, block, 0, stream>>>(x, W, out);
}

// Round 3
// 161.479 us; speedup vs baseline: 2.9482x; 2.8226x over previous
//
#include <hip/hip_runtime.h>

#define RDIM 1152
#define CIN  8
#define COUT 16
#define CDIM 10
#define BDIM 256
#define BLOCK 384
#define AUNITS 12                // phase A: (1152 rows * 4 quarters) / 384 threads
#define BUNITS 3                 // phase B: 1152 rows / 384 threads
#define NWAVES (BLOCK / 64)
#define NWG (CDIM * BDIM)        // 2560, divisible by 8
#define EPS 1e-7f

// Swizzled float4 slot for u_hat in LDS: row r, o-quarter j -> dword offset.
// XOR of (r>>1)&3 into the quarter index + the natural 16*(r&1) bit spreads
// any 8 consecutive rows (read phase) and any (16 rows x 4 quarters) set
// (write phase) across all eight 4-bank groups -> conflict-free b128 access.
__device__ __forceinline__ int uh_off(int r, int j) {
    return r * COUT + ((j ^ ((r >> 1) & 3)) << 2);
}

__global__ __launch_bounds__(BLOCK, 3) void caps_route(
    const float* __restrict__ x, const float* __restrict__ W,
    float* __restrict__ out)
{
    // XCD-aware bijective swizzle (2560 = 8 * 320)
    const int orig = blockIdx.x;
    const int wg   = (orig & 7) * (NWG / 8) + (orig >> 3);
    const int c    = wg / BDIM;
    const int b    = wg % BDIM;

    const int tid  = threadIdx.x;
    const int lane = tid & 63;
    const int wave = tid >> 6;

    __shared__ float uh[RDIM * COUT];        // 72 KB, swizzled
    __shared__ float red[NWAVES][COUT];
    __shared__ float scalm[NWAVES];
    __shared__ float scalz[NWAVES];

    const float* __restrict__ Wc = W + (size_t)c * RDIM * CIN * COUT;
    const float* __restrict__ xb = x + (size_t)b * RDIM * CIN;

    // ---------- Phase A: u_hat -> LDS (coalesced W reads) ----------
    {
        const int oq   = tid & 3;            // o-quarter
        const int rsub = tid >> 2;           // 0..95
        #pragma unroll
        for (int k = 0; k < AUNITS; ++k) {
            const int r = k * 96 + rsub;
            const float4* xp = (const float4*)(xb + (size_t)r * CIN);
            float4 x0 = xp[0], x1 = xp[1];
            float xr[CIN] = {x0.x, x0.y, x0.z, x0.w, x1.x, x1.y, x1.z, x1.w};

            const float* wrow = Wc + (size_t)r * (CIN * COUT) + oq * 4;
            float a0 = 0.f, a1 = 0.f, a2 = 0.f, a3 = 0.f;
            #pragma unroll
            for (int i = 0; i < CIN; ++i) {
                float4 w = *(const float4*)(wrow + i * COUT);
                a0 = fmaf(xr[i], w.x, a0);
                a1 = fmaf(xr[i], w.y, a1);
                a2 = fmaf(xr[i], w.z, a2);
                a3 = fmaf(xr[i], w.w, a3);
            }
            *(float4*)&uh[uh_off(r, oq)] = make_float4(a0, a1, a2, a3);
        }
    }
    __syncthreads();

    // ---------- Phase B: routing; each thread owns rows r = k*384 + tid ----------
    float bb[BUNITS];
    #pragma unroll
    for (int k = 0; k < BUNITS; ++k) bb[k] = 0.0f;
    float v[COUT];

    #pragma unroll
    for (int it = 0; it < 3; ++it) {
        // 1) softmax max over R
        float m = bb[0];
        #pragma unroll
        for (int k = 1; k < BUNITS; ++k) m = fmaxf(m, bb[k]);
        #pragma unroll
        for (int off = 32; off >= 1; off >>= 1) m = fmaxf(m, __shfl_xor(m, off));
        if (lane == 0) scalm[wave] = m;
        __syncthreads();
        m = scalm[0];
        #pragma unroll
        for (int w2 = 1; w2 < NWAVES; ++w2) m = fmaxf(m, scalm[w2]);

        // 2) e = exp(b-m); partial Z and weighted sums over owned rows
        float e[BUNITS];
        float Zp = 0.f;
        float sp[COUT];
        #pragma unroll
        for (int o = 0; o < COUT; ++o) sp[o] = 0.f;
        #pragma unroll
        for (int k = 0; k < BUNITS; ++k) {
            const int r = k * BLOCK + tid;
            e[k] = expf(bb[k] - m);
            Zp += e[k];
            #pragma unroll
            for (int j = 0; j < 4; ++j) {
                float4 u = *(const float4*)&uh[uh_off(r, j)];
                sp[j * 4 + 0] = fmaf(e[k], u.x, sp[j * 4 + 0]);
                sp[j * 4 + 1] = fmaf(e[k], u.y, sp[j * 4 + 1]);
                sp[j * 4 + 2] = fmaf(e[k], u.z, sp[j * 4 + 2]);
                sp[j * 4 + 3] = fmaf(e[k], u.w, sp[j * 4 + 3]);
            }
        }
        #pragma unroll
        for (int off = 32; off >= 1; off >>= 1) {
            Zp += __shfl_xor(Zp, off);
            #pragma unroll
            for (int o = 0; o < COUT; ++o) sp[o] += __shfl_xor(sp[o], off);
        }
        if (lane == 0) {
            scalz[wave] = Zp;
            #pragma unroll
            for (int o = 0; o < COUT; ++o) red[wave][o] = sp[o];
        }
        __syncthreads();

        // 3) finalize s, squash (redundant on all threads; LDS broadcasts)
        float Z = 0.f;
        #pragma unroll
        for (int w2 = 0; w2 < NWAVES; ++w2) Z += scalz[w2];
        const float invZ = 1.0f / Z;
        float sn = 0.f;
        #pragma unroll
        for (int o = 0; o < COUT; ++o) {
            float acc = 0.f;
            #pragma unroll
            for (int w2 = 0; w2 < NWAVES; ++w2) acc += red[w2][o];
            acc *= invZ;
            v[o] = acc;
            sn = fmaf(acc, acc, sn);
        }
        const float scale = (sn / (1.0f + sn)) / sqrtf(sn + EPS);
        #pragma unroll
        for (int o = 0; o < COUT; ++o) v[o] *= scale;

        // 4) agreement update: full 16-o dot per owned row (no cross-lane)
        if (it < 2) {
            #pragma unroll
            for (int k = 0; k < BUNITS; ++k) {
                const int r = k * BLOCK + tid;
                float a = 0.f;
                #pragma unroll
                for (int j = 0; j < 4; ++j) {
                    float4 u = *(const float4*)&uh[uh_off(r, j)];
                    a = fmaf(u.x, v[j * 4 + 0], a);
                    a = fmaf(u.y, v[j * 4 + 1], a);
                    a = fmaf(u.z, v[j * 4 + 2], a);
                    a = fmaf(u.w, v[j * 4 + 3], a);
                }
                bb[k] += a;
            }
        }
    }

    // ---------- write output [C,B,1,1,O]: one lane, 4x float4 ----------
    if (tid == 0) {
        float* op = out + ((size_t)c * BDIM + b) * COUT;
        *(float4*)(op + 0)  = make_float4(v[0],  v[1],  v[2],  v[3]);
        *(float4*)(op + 4)  = make_float4(v[4],  v[5],  v[6],  v[7]);
        *(float4*)(op + 8)  = make_float4(v[8],  v[9],  v[10], v[11]);
        *(float4*)(op + 12) = make_float4(v[12], v[13], v[14], v[15]);
    }
}

extern "C" void kernel_launch(void* const* d_in, const int* in_sizes, int n_in,
                              void* d_out, int out_size, void* d_ws, size_t ws_size,
                              hipStream_t stream) {
    const float* x = (const float*)d_in[0];   // [256,1152,8]
    const float* W = (const float*)d_in[1];   // [10,1152,8,16]
    float* out = (float*)d_out;               // [10,256,1,1,16]

    dim3 grid(NWG);
    dim3 block(BLOCK);
    caps_route<<<grid, block, 0, stream>>>(x, W, out);
}